// Round 2
// baseline (7330.861 us; speedup 1.0000x reference)
//
#include <hip/hip_runtime.h>
#include <stdint.h>

#define KSTEPS 20
#define EPB 4          // batch elements per block
#define NBLOCKS 1024   // 4096 / EPB
#define NTHREADS 512

// ---- LDS layout (bytes) ----
// wq    : uint32 [4][128][64]   (bf16-pairs, pair-rotated swizzle) = 131072
// hcatT : float  [256][4]                                          =   4096  @131072
// h0T   : float  [256][4]                                          =   4096  @135168
// xbuf  : float  [4][128]                                          =   2048  @139264
// part  : float  [3][2][128][4]                                    =  12288  @141312
// total = 153600
#define SMEM_BYTES 153600

static __device__ __forceinline__ float bflo(uint32_t u) {
    union { uint32_t u; float f; } v; v.u = u << 16; return v.f;
}
static __device__ __forceinline__ float bfhi(uint32_t u) {
    union { uint32_t u; float f; } v; v.u = u & 0xffff0000u; return v.f;
}
static __device__ __forceinline__ uint32_t f2bf(float x) {  // RNE round to bf16 (as u16)
    union { float f; uint32_t u; } v; v.f = x;
    return (v.u + 0x7fffu + ((v.u >> 16) & 1u)) >> 16;
}
static __device__ __forceinline__ uint32_t packbf2(float a, float b) {
    return f2bf(a) | (f2bf(b) << 16);
}
static __device__ __forceinline__ uint32_t u4get(const uint4& v, int i) {
    switch (i) { case 0: return v.x; case 1: return v.y; case 2: return v.z; default: return v.w; }
}

// Pack shared MLP weights fp32 -> bf16 in layout [c][r][m] : Wp[(c*R + r)*8 + m] = W[r][8c+m]
// W0: R=256 (65536 elems), W1: R=256 (65536), V: R=128 (32768). Total 163840 bf16 = 320 KB.
__global__ void prep_kernel(const float* __restrict__ W0, const float* __restrict__ W1,
                            const float* __restrict__ V, uint16_t* __restrict__ out)
{
    int i = blockIdx.x * 256 + threadIdx.x;   // 640 blocks * 256 = 163840
    float v;
    if (i < 65536) {
        int c = i >> 11, rest = i & 2047, r = rest >> 3, m = rest & 7;
        v = W0[r * 256 + c * 8 + m];
    } else if (i < 131072) {
        int j = i - 65536;
        int c = j >> 11, rest = j & 2047, r = rest >> 3, m = rest & 7;
        v = W1[r * 256 + c * 8 + m];
    } else {
        int j = i - 131072;
        int c = j >> 10, rest = j & 1023, r = rest >> 3, m = rest & 7;
        v = V[r * 256 + c * 8 + m];
    }
    out[i] = (uint16_t)f2bf(v);
}

// Round-1 post-mortem: phase time (43K cyc) == wp bytes/phase (128KB/block) at the
// latency-limited per-CU HBM rate (3 B/cy). The kernel was bound by re-reading the
// 320KB bf16 weight image from global EVERY k-step (6.55 GB of L2-missing traffic).
// Fix: weights are loop-invariant -> hoist each thread's 640 B slice (40 uint4 =
// 160 VGPRs) into registers ONCE. LDS caps us at 1 block/CU = 2 waves/EU, so the
// 256-VGPR budget (pinned via waves_per_eu(2,2)) is free occupancy-wise.
__global__
__attribute__((amdgpu_flat_work_group_size(512, 512), amdgpu_waves_per_eu(2, 2)))
void mlprnn_main(
    const float* __restrict__ w, const float* __restrict__ b,
    const uint16_t* __restrict__ wp, float* __restrict__ out)
{
    extern __shared__ char smem[];
    uint32_t* wq    = (uint32_t*)smem;
    float*    hcatT = (float*)(smem + 131072);
    float*    h0T   = (float*)(smem + 135168);
    float*    xbuf  = (float*)(smem + 139264);
    float4*   hcatT4 = (float4*)hcatT;
    float4*   h0T4   = (float4*)h0T;
    float4*   part4  = (float4*)(smem + 141312);

    const int t  = threadIdx.x;
    const int e0 = blockIdx.x * EPB;

    // ---- MLP role: row-pair rp/rp+128, K-quarter jq ----
    const int rp = t & 127;
    const int jq = t >> 7;   // 0..3

    // ---- hoist this thread's weight slices into registers (loop-invariant) ----
    // W0: rows rp, rp+128 x cols [jq*64, jq*64+64)  -> 16 uint4
    // W1: same                                      -> 16 uint4
    // V : row rp x cols [jq*64, jq*64+64)           ->  8 uint4
    uint4 rw0[16], rw1[16], rv[8];
    {
        const uint4* w0p = (const uint4*)wp;       // [32][256] uint4 (8 bf16 each)
        const uint4* w1p = w0p + 32 * 256;
        const uint4* vp  = w1p + 32 * 256;         // [32][128]
        #pragma unroll
        for (int ci = 0; ci < 8; ++ci) {
            int c = jq * 8 + ci;
            rw0[ci]     = w0p[c * 256 + rp];
            rw0[8 + ci] = w0p[c * 256 + rp + 128];
            rw1[ci]     = w1p[c * 256 + rp];
            rw1[8 + ci] = w1p[c * 256 + rp + 128];
            rv[ci]      = vp[c * 128 + rp];
        }
    }

    // ---- load this block's 4 w matrices -> LDS bf16, pair-rotated swizzle ----
    // flat float4 index g over [4][128 rows][32 quads]; store quad q of row r at slot (q+r)&31.
    {
        const float4* wg = (const float4*)w;
        for (int it = 0; it < 32; ++it) {
            int g  = it * NTHREADS + t;       // 0..16383
            int e  = g >> 12;
            int gg = g & 4095;
            int r  = gg >> 5, q = gg & 31;
            float4 f = wg[(size_t)(e0 + e) * 4096 + gg];
            int s = (q + r) & 31;
            uint32_t* dst = wq + ((e * 128 + r) * 64 + 2 * s);
            dst[0] = packbf2(f.x, f.y);
            dst[1] = packbf2(f.z, f.w);
        }
    }
    // init x = 0 and hcat upper half (x part) = 0
    xbuf[t] = 0.f;
    if (t < 128) hcatT4[128 + t] = make_float4(0.f, 0.f, 0.f, 0.f);
    __syncthreads();

    // ---- matvec role: 2 waves per element, lane-per-row ----
    const int e_mv = t >> 7;                       // element 0..3
    const int r_mv = ((t >> 6) & 1) * 64 + (t & 63); // row 0..127
    const float breg = b[(size_t)(e0 + e_mv) * 128 + r_mv];
    const uint32_t* wrow = wq + ((e_mv * 128 + r_mv) * 64);
    const float4*   xv   = (const float4*)(xbuf + e_mv * 128);
    const int hcat_wr = r_mv * 4 + e_mv;

    for (int k = 0; k < KSTEPS; ++k) {
        // ================= grad = w @ x - b ;  hcatT[r] = -grad =================
        {
            float acc = 0.f;
            #pragma unroll
            for (int j4 = 0; j4 < 32; ++j4) {
                int s = (j4 + r_mv) & 31;
                uint2 u = *(const uint2*)(wrow + 2 * s);
                float4 xq = xv[j4];
                acc += bflo(u.x) * xq.x + bfhi(u.x) * xq.y
                     + bflo(u.y) * xq.z + bfhi(u.y) * xq.w;
            }
            hcatT[hcat_wr] = breg - acc;   // -grad
        }
        __syncthreads();

        // ================= h0 = relu(W0 @ hcat) -> h0T =================
        {
            float4 a0 = make_float4(0.f, 0.f, 0.f, 0.f);
            float4 a1 = make_float4(0.f, 0.f, 0.f, 0.f);
            #pragma unroll
            for (int ci = 0; ci < 8; ++ci) {
                int c = jq * 8 + ci;
                uint4 wv0 = rw0[ci];
                uint4 wv1 = rw0[8 + ci];
                #pragma unroll
                for (int m = 0; m < 8; ++m) {
                    float4 h = hcatT4[c * 8 + m];
                    uint32_t q0 = u4get(wv0, m >> 1), q1 = u4get(wv1, m >> 1);
                    float f0 = (m & 1) ? bfhi(q0) : bflo(q0);
                    float f1 = (m & 1) ? bfhi(q1) : bflo(q1);
                    a0.x += f0 * h.x; a0.y += f0 * h.y; a0.z += f0 * h.z; a0.w += f0 * h.w;
                    a1.x += f1 * h.x; a1.y += f1 * h.y; a1.z += f1 * h.z; a1.w += f1 * h.w;
                }
            }
            if (jq > 0) {
                part4[((jq - 1) * 2 + 0) * 128 + rp] = a0;
                part4[((jq - 1) * 2 + 1) * 128 + rp] = a1;
            }
            __syncthreads();
            if (jq == 0) {
                #pragma unroll
                for (int q = 0; q < 3; ++q) {
                    float4 p0 = part4[(q * 2 + 0) * 128 + rp];
                    float4 p1 = part4[(q * 2 + 1) * 128 + rp];
                    a0.x += p0.x; a0.y += p0.y; a0.z += p0.z; a0.w += p0.w;
                    a1.x += p1.x; a1.y += p1.y; a1.z += p1.z; a1.w += p1.w;
                }
                a0.x = fmaxf(a0.x, 0.f); a0.y = fmaxf(a0.y, 0.f); a0.z = fmaxf(a0.z, 0.f); a0.w = fmaxf(a0.w, 0.f);
                a1.x = fmaxf(a1.x, 0.f); a1.y = fmaxf(a1.y, 0.f); a1.z = fmaxf(a1.z, 0.f); a1.w = fmaxf(a1.w, 0.f);
                h0T4[rp]       = a0;
                h0T4[rp + 128] = a1;
            }
            __syncthreads();
        }

        // ================= h1 = relu(W1 @ h0) -> hcatT (reused as h1T) =================
        {
            float4 a0 = make_float4(0.f, 0.f, 0.f, 0.f);
            float4 a1 = make_float4(0.f, 0.f, 0.f, 0.f);
            #pragma unroll
            for (int ci = 0; ci < 8; ++ci) {
                int c = jq * 8 + ci;
                uint4 wv0 = rw1[ci];
                uint4 wv1 = rw1[8 + ci];
                #pragma unroll
                for (int m = 0; m < 8; ++m) {
                    float4 h = h0T4[c * 8 + m];
                    uint32_t q0 = u4get(wv0, m >> 1), q1 = u4get(wv1, m >> 1);
                    float f0 = (m & 1) ? bfhi(q0) : bflo(q0);
                    float f1 = (m & 1) ? bfhi(q1) : bflo(q1);
                    a0.x += f0 * h.x; a0.y += f0 * h.y; a0.z += f0 * h.z; a0.w += f0 * h.w;
                    a1.x += f1 * h.x; a1.y += f1 * h.y; a1.z += f1 * h.z; a1.w += f1 * h.w;
                }
            }
            if (jq > 0) {
                part4[((jq - 1) * 2 + 0) * 128 + rp] = a0;
                part4[((jq - 1) * 2 + 1) * 128 + rp] = a1;
            }
            __syncthreads();
            if (jq == 0) {
                #pragma unroll
                for (int q = 0; q < 3; ++q) {
                    float4 p0 = part4[(q * 2 + 0) * 128 + rp];
                    float4 p1 = part4[(q * 2 + 1) * 128 + rp];
                    a0.x += p0.x; a0.y += p0.y; a0.z += p0.z; a0.w += p0.w;
                    a1.x += p1.x; a1.y += p1.y; a1.z += p1.z; a1.w += p1.w;
                }
                a0.x = fmaxf(a0.x, 0.f); a0.y = fmaxf(a0.y, 0.f); a0.z = fmaxf(a0.z, 0.f); a0.w = fmaxf(a0.w, 0.f);
                a1.x = fmaxf(a1.x, 0.f); a1.y = fmaxf(a1.y, 0.f); a1.z = fmaxf(a1.z, 0.f); a1.w = fmaxf(a1.w, 0.f);
                hcatT4[rp]       = a0;   // h1T rows 0..127
                hcatT4[rp + 128] = a1;   // h1T rows 128..255
            }
            __syncthreads();
        }

        // ================= x_new = V @ h1 ; update xbuf, hcat upper, (final) out =================
        {
            float4 a = make_float4(0.f, 0.f, 0.f, 0.f);
            #pragma unroll
            for (int ci = 0; ci < 8; ++ci) {
                int c = jq * 8 + ci;
                uint4 wv = rv[ci];
                #pragma unroll
                for (int m = 0; m < 8; ++m) {
                    float4 h = hcatT4[c * 8 + m];   // h1T
                    uint32_t qw = u4get(wv, m >> 1);
                    float f = (m & 1) ? bfhi(qw) : bflo(qw);
                    a.x += f * h.x; a.y += f * h.y; a.z += f * h.z; a.w += f * h.w;
                }
            }
            if (jq > 0) part4[(jq - 1) * 128 + rp] = a;
            __syncthreads();
            if (jq == 0) {
                #pragma unroll
                for (int q = 0; q < 3; ++q) {
                    float4 p = part4[q * 128 + rp];
                    a.x += p.x; a.y += p.y; a.z += p.z; a.w += p.w;
                }
                xbuf[0 * 128 + rp] = a.x;
                xbuf[1 * 128 + rp] = a.y;
                xbuf[2 * 128 + rp] = a.z;
                xbuf[3 * 128 + rp] = a.w;
                hcatT4[128 + rp] = a;      // x part of next hcat
                if (k == KSTEPS - 1) {
                    out[(size_t)(e0 + 0) * 128 + rp] = a.x;
                    out[(size_t)(e0 + 1) * 128 + rp] = a.y;
                    out[(size_t)(e0 + 2) * 128 + rp] = a.z;
                    out[(size_t)(e0 + 3) * 128 + rp] = a.w;
                }
            }
            __syncthreads();
        }
    }
}

extern "C" void kernel_launch(void* const* d_in, const int* in_sizes, int n_in,
                              void* d_out, int out_size, void* d_ws, size_t ws_size,
                              hipStream_t stream)
{
    const float* w  = (const float*)d_in[0];   // [4096,128,128]
    const float* b  = (const float*)d_in[1];   // [4096,128]
    const float* W0 = (const float*)d_in[2];   // [256,256]
    const float* W1 = (const float*)d_in[3];   // [256,256]
    const float* V  = (const float*)d_in[4];   // [128,256]
    float* out = (float*)d_out;                // [4096,128]
    uint16_t* wp = (uint16_t*)d_ws;            // 320 KB packed bf16 weights

    prep_kernel<<<640, 256, 0, stream>>>(W0, W1, V, wp);

    hipFuncSetAttribute((const void*)mlprnn_main,
                        hipFuncAttributeMaxDynamicSharedMemorySize, SMEM_BYTES);
    mlprnn_main<<<NBLOCKS, NTHREADS, SMEM_BYTES, stream>>>(w, b, wp, out);
}

// Round 3
// 744.093 us; speedup vs baseline: 9.8521x; 9.8521x over previous
//
#include <hip/hip_runtime.h>
#include <stdint.h>

#define KSTEPS 20
#define EPB 4          // batch elements per block
#define NBLOCKS 1024   // 4096 / EPB
#define NTHREADS 512

// ---- LDS layout (bytes) ----
// wq    : uint32 [4][128][64]   (bf16-pairs, pair-rotated swizzle) = 131072
// hcatT : float  [256][4]                                          =   4096  @131072
// h0T   : float  [256][4]                                          =   4096  @135168
// xbuf  : float  [4][128]                                          =   2048  @139264
// part  : float  [3][2][128][4]                                    =  12288  @141312
// total = 153600
#define SMEM_BYTES 153600

static __device__ __forceinline__ float bflo(uint32_t u) {
    union { uint32_t u; float f; } v; v.u = u << 16; return v.f;
}
static __device__ __forceinline__ float bfhi(uint32_t u) {
    union { uint32_t u; float f; } v; v.u = u & 0xffff0000u; return v.f;
}
static __device__ __forceinline__ uint32_t f2bf(float x) {  // RNE round to bf16 (as u16)
    union { float f; uint32_t u; } v; v.f = x;
    return (v.u + 0x7fffu + ((v.u >> 16) & 1u)) >> 16;
}
static __device__ __forceinline__ uint32_t packbf2(float a, float b) {
    return f2bf(a) | (f2bf(b) << 16);
}
static __device__ __forceinline__ uint32_t u4get(const uint4& v, int i) {
    switch (i) { case 0: return v.x; case 1: return v.y; case 2: return v.z; default: return v.w; }
}

// Pack shared MLP weights fp32 -> bf16 in layout [c][r][m] : Wp[(c*R + r)*8 + m] = W[r][8c+m]
// W0: R=256 (65536 elems), W1: R=256 (65536), V: R=128 (32768). Total 163840 bf16 = 320 KB.
__global__ void prep_kernel(const float* __restrict__ W0, const float* __restrict__ W1,
                            const float* __restrict__ V, uint16_t* __restrict__ out)
{
    int i = blockIdx.x * 256 + threadIdx.x;   // 640 blocks * 256 = 163840
    float v;
    if (i < 65536) {
        int c = i >> 11, rest = i & 2047, r = rest >> 3, m = rest & 7;
        v = W0[r * 256 + c * 8 + m];
    } else if (i < 131072) {
        int j = i - 65536;
        int c = j >> 11, rest = j & 2047, r = rest >> 3, m = rest & 7;
        v = W1[r * 256 + c * 8 + m];
    } else {
        int j = i - 131072;
        int c = j >> 10, rest = j & 1023, r = rest >> 3, m = rest & 7;
        v = V[r * 256 + c * 8 + m];
    }
    out[i] = (uint16_t)f2bf(v);
}

// Round-2 post-mortem: the VGPR budget on this kernel is HARD-CAPPED at 128
// (waves_per_eu(2,2) changed SGPRs but not VGPRs; the 160 hoisted weight regs
// spilled to scratch -> private 10.5 MB/XCD working set -> guaranteed L2 miss ->
// regression). R0/R1 also spilled (~1.7 GB WRITE_SIZE): full unroll keeps 16 uint4
// weight loads + accs + pipelined LDS reads live (~150-190 regs demand).
// Those scratch round-trips thrash L2, which is why the 320 KB wp image misses L2
// and streams 6.5 GB from HBM.
// Fix: design for <=128 regs. Per-phase wp reads stay (they L2-hit once scratch
// stops thrashing); unrolls bounded (#pragma unroll 4 on ci => 8 uint4 in flight,
// #pragma unroll 8 on matvec) so live set peaks ~90 and spills vanish.
__global__
__attribute__((amdgpu_flat_work_group_size(512, 512), amdgpu_waves_per_eu(2, 2)))
void mlprnn_main(
    const float* __restrict__ w, const float* __restrict__ b,
    const uint16_t* __restrict__ wp, float* __restrict__ out)
{
    extern __shared__ char smem[];
    uint32_t* wq    = (uint32_t*)smem;
    float*    hcatT = (float*)(smem + 131072);
    float*    h0T   = (float*)(smem + 135168);
    float*    xbuf  = (float*)(smem + 139264);
    float4*   hcatT4 = (float4*)hcatT;
    float4*   h0T4   = (float4*)h0T;
    float4*   part4  = (float4*)(smem + 141312);

    const int t  = threadIdx.x;
    const int e0 = blockIdx.x * EPB;

    // ---- load this block's 4 w matrices -> LDS bf16, pair-rotated swizzle ----
    // flat float4 index g over [4][128 rows][32 quads]; store quad q of row r at slot (q+r)&31.
    {
        const float4* wg = (const float4*)w;
        for (int it = 0; it < 32; ++it) {
            int g  = it * NTHREADS + t;       // 0..16383
            int e  = g >> 12;
            int gg = g & 4095;
            int r  = gg >> 5, q = gg & 31;
            float4 f = wg[(size_t)(e0 + e) * 4096 + gg];
            int s = (q + r) & 31;
            uint32_t* dst = wq + ((e * 128 + r) * 64 + 2 * s);
            dst[0] = packbf2(f.x, f.y);
            dst[1] = packbf2(f.z, f.w);
        }
    }
    // init x = 0 and hcat upper half (x part) = 0
    xbuf[t] = 0.f;
    if (t < 128) hcatT4[128 + t] = make_float4(0.f, 0.f, 0.f, 0.f);
    __syncthreads();

    // ---- matvec role: 2 waves per element, lane-per-row ----
    const int e_mv = t >> 7;                       // element 0..3
    const int r_mv = ((t >> 6) & 1) * 64 + (t & 63); // row 0..127
    const float breg = b[(size_t)(e0 + e_mv) * 128 + r_mv];
    const uint32_t* wrow = wq + ((e_mv * 128 + r_mv) * 64);
    const float4*   xv   = (const float4*)(xbuf + e_mv * 128);
    const int hcat_wr = r_mv * 4 + e_mv;

    // ---- MLP role: row-pair rp/rp+128, K-quarter jq ----
    const int rp = t & 127;
    const int jq = t >> 7;   // 0..3

    const uint4* w0p = (const uint4*)wp;       // [32][256] uint4 (8 bf16 each)
    const uint4* w1p = w0p + 32 * 256;
    const uint4* vp  = w1p + 32 * 256;         // [32][128]

    for (int k = 0; k < KSTEPS; ++k) {
        // ================= grad = w @ x - b ;  hcatT[r] = -grad =================
        {
            float acc = 0.f;
            #pragma unroll 8
            for (int j4 = 0; j4 < 32; ++j4) {
                int s = (j4 + r_mv) & 31;
                uint2 u = *(const uint2*)(wrow + 2 * s);
                float4 xq = xv[j4];
                acc += bflo(u.x) * xq.x + bfhi(u.x) * xq.y
                     + bflo(u.y) * xq.z + bfhi(u.y) * xq.w;
            }
            hcatT[hcat_wr] = breg - acc;   // -grad
        }
        __syncthreads();

        // ================= h0 = relu(W0 @ hcat) -> h0T =================
        {
            float4 a0 = make_float4(0.f, 0.f, 0.f, 0.f);
            float4 a1 = make_float4(0.f, 0.f, 0.f, 0.f);
            #pragma unroll 4
            for (int ci = 0; ci < 8; ++ci) {
                int c = jq * 8 + ci;
                uint4 wv0 = w0p[c * 256 + rp];
                uint4 wv1 = w0p[c * 256 + rp + 128];
                #pragma unroll
                for (int m = 0; m < 8; ++m) {
                    float4 h = hcatT4[c * 8 + m];
                    uint32_t q0 = u4get(wv0, m >> 1), q1 = u4get(wv1, m >> 1);
                    float f0 = (m & 1) ? bfhi(q0) : bflo(q0);
                    float f1 = (m & 1) ? bfhi(q1) : bflo(q1);
                    a0.x += f0 * h.x; a0.y += f0 * h.y; a0.z += f0 * h.z; a0.w += f0 * h.w;
                    a1.x += f1 * h.x; a1.y += f1 * h.y; a1.z += f1 * h.z; a1.w += f1 * h.w;
                }
            }
            if (jq > 0) {
                part4[((jq - 1) * 2 + 0) * 128 + rp] = a0;
                part4[((jq - 1) * 2 + 1) * 128 + rp] = a1;
            }
            __syncthreads();
            if (jq == 0) {
                #pragma unroll
                for (int q = 0; q < 3; ++q) {
                    float4 p0 = part4[(q * 2 + 0) * 128 + rp];
                    float4 p1 = part4[(q * 2 + 1) * 128 + rp];
                    a0.x += p0.x; a0.y += p0.y; a0.z += p0.z; a0.w += p0.w;
                    a1.x += p1.x; a1.y += p1.y; a1.z += p1.z; a1.w += p1.w;
                }
                a0.x = fmaxf(a0.x, 0.f); a0.y = fmaxf(a0.y, 0.f); a0.z = fmaxf(a0.z, 0.f); a0.w = fmaxf(a0.w, 0.f);
                a1.x = fmaxf(a1.x, 0.f); a1.y = fmaxf(a1.y, 0.f); a1.z = fmaxf(a1.z, 0.f); a1.w = fmaxf(a1.w, 0.f);
                h0T4[rp]       = a0;
                h0T4[rp + 128] = a1;
            }
            __syncthreads();
        }

        // ================= h1 = relu(W1 @ h0) -> hcatT (reused as h1T) =================
        {
            float4 a0 = make_float4(0.f, 0.f, 0.f, 0.f);
            float4 a1 = make_float4(0.f, 0.f, 0.f, 0.f);
            #pragma unroll 4
            for (int ci = 0; ci < 8; ++ci) {
                int c = jq * 8 + ci;
                uint4 wv0 = w1p[c * 256 + rp];
                uint4 wv1 = w1p[c * 256 + rp + 128];
                #pragma unroll
                for (int m = 0; m < 8; ++m) {
                    float4 h = h0T4[c * 8 + m];
                    uint32_t q0 = u4get(wv0, m >> 1), q1 = u4get(wv1, m >> 1);
                    float f0 = (m & 1) ? bfhi(q0) : bflo(q0);
                    float f1 = (m & 1) ? bfhi(q1) : bflo(q1);
                    a0.x += f0 * h.x; a0.y += f0 * h.y; a0.z += f0 * h.z; a0.w += f0 * h.w;
                    a1.x += f1 * h.x; a1.y += f1 * h.y; a1.z += f1 * h.z; a1.w += f1 * h.w;
                }
            }
            if (jq > 0) {
                part4[((jq - 1) * 2 + 0) * 128 + rp] = a0;
                part4[((jq - 1) * 2 + 1) * 128 + rp] = a1;
            }
            __syncthreads();
            if (jq == 0) {
                #pragma unroll
                for (int q = 0; q < 3; ++q) {
                    float4 p0 = part4[(q * 2 + 0) * 128 + rp];
                    float4 p1 = part4[(q * 2 + 1) * 128 + rp];
                    a0.x += p0.x; a0.y += p0.y; a0.z += p0.z; a0.w += p0.w;
                    a1.x += p1.x; a1.y += p1.y; a1.z += p1.z; a1.w += p1.w;
                }
                a0.x = fmaxf(a0.x, 0.f); a0.y = fmaxf(a0.y, 0.f); a0.z = fmaxf(a0.z, 0.f); a0.w = fmaxf(a0.w, 0.f);
                a1.x = fmaxf(a1.x, 0.f); a1.y = fmaxf(a1.y, 0.f); a1.z = fmaxf(a1.z, 0.f); a1.w = fmaxf(a1.w, 0.f);
                hcatT4[rp]       = a0;   // h1T rows 0..127
                hcatT4[rp + 128] = a1;   // h1T rows 128..255
            }
            __syncthreads();
        }

        // ================= x_new = V @ h1 ; update xbuf, hcat upper, (final) out =================
        {
            float4 a = make_float4(0.f, 0.f, 0.f, 0.f);
            #pragma unroll 4
            for (int ci = 0; ci < 8; ++ci) {
                int c = jq * 8 + ci;
                uint4 wv = vp[c * 128 + rp];
                #pragma unroll
                for (int m = 0; m < 8; ++m) {
                    float4 h = hcatT4[c * 8 + m];   // h1T
                    uint32_t qw = u4get(wv, m >> 1);
                    float f = (m & 1) ? bfhi(qw) : bflo(qw);
                    a.x += f * h.x; a.y += f * h.y; a.z += f * h.z; a.w += f * h.w;
                }
            }
            if (jq > 0) part4[(jq - 1) * 128 + rp] = a;
            __syncthreads();
            if (jq == 0) {
                #pragma unroll
                for (int q = 0; q < 3; ++q) {
                    float4 p = part4[q * 128 + rp];
                    a.x += p.x; a.y += p.y; a.z += p.z; a.w += p.w;
                }
                xbuf[0 * 128 + rp] = a.x;
                xbuf[1 * 128 + rp] = a.y;
                xbuf[2 * 128 + rp] = a.z;
                xbuf[3 * 128 + rp] = a.w;
                hcatT4[128 + rp] = a;      // x part of next hcat
                if (k == KSTEPS - 1) {
                    out[(size_t)(e0 + 0) * 128 + rp] = a.x;
                    out[(size_t)(e0 + 1) * 128 + rp] = a.y;
                    out[(size_t)(e0 + 2) * 128 + rp] = a.z;
                    out[(size_t)(e0 + 3) * 128 + rp] = a.w;
                }
            }
            __syncthreads();
        }
    }
}

extern "C" void kernel_launch(void* const* d_in, const int* in_sizes, int n_in,
                              void* d_out, int out_size, void* d_ws, size_t ws_size,
                              hipStream_t stream)
{
    const float* w  = (const float*)d_in[0];   // [4096,128,128]
    const float* b  = (const float*)d_in[1];   // [4096,128]
    const float* W0 = (const float*)d_in[2];   // [256,256]
    const float* W1 = (const float*)d_in[3];   // [256,256]
    const float* V  = (const float*)d_in[4];   // [128,256]
    float* out = (float*)d_out;                // [4096,128]
    uint16_t* wp = (uint16_t*)d_ws;            // 320 KB packed bf16 weights

    prep_kernel<<<640, 256, 0, stream>>>(W0, W1, V, wp);

    hipFuncSetAttribute((const void*)mlprnn_main,
                        hipFuncAttributeMaxDynamicSharedMemorySize, SMEM_BYTES);
    mlprnn_main<<<NBLOCKS, NTHREADS, SMEM_BYTES, stream>>>(w, b, wp, out);
}